// Round 8
// baseline (463.577 us; speedup 1.0000x reference)
//
#include <hip/hip_runtime.h>
#include <hip/hip_bf16.h>
#include <stdint.h>

// GAT forward, N=8192, IN=256, OUT=128. Inputs fp32 (adj int32), output fp32.
// softmax_j(a1_i + a2_j | adj) == adj_ij*exp(a2_j)/sum_j adj_ij*exp(a2_j)  (a1 cancels)
// -> out = (adj @ (w*h)) / (adj @ w). One big GEMM over adj (268 MB read = floor).
// k_agg v5: NO global atomics (rounds 5&7 both plateaued at ~175us with 9.4M
// device-scope atomics write-through = 37MB WRITE_SIZE -> memory-side atomic
// ceiling ~22 ops/cyc). One block = 32 rows x full K (8 waves x 1024), LDS
// reduce, fused divide-epilogue, plain stores. Barrier-free K-loop with
// depth-1 register prefetch of A and B for MLP.

typedef __attribute__((ext_vector_type(8))) short short8;
typedef __attribute__((ext_vector_type(4))) float float4v;

static __device__ __forceinline__ unsigned short f2bf(float f) {
    union { float f; uint32_t i; } v; v.f = f;
    uint32_t r = v.i + 0x7FFFu + ((v.i >> 16) & 1u);
    return (unsigned short)(r >> 16);
}

// pack 8 int32 (0/1) -> 8 packed bf16 {0.0, 1.0}
static __device__ __forceinline__ short8 pack01(int4 a, int4 b) {
    union { uint32_t u[4]; short8 s; } v;
    v.u[0] = (uint32_t)(a.x | (a.y << 16)) * 0x3F80u;
    v.u[1] = (uint32_t)(a.z | (a.w << 16)) * 0x3F80u;
    v.u[2] = (uint32_t)(b.x | (b.y << 16)) * 0x3F80u;
    v.u[3] = (uint32_t)(b.z | (b.w << 16)) * 0x3F80u;
    return v.s;
}

// ---- WT[n][k] = bf16(W[k][n]) : 128x256 k-major ----
__global__ void k_transpose_w(const float* __restrict__ W, unsigned short* __restrict__ WT) {
    __shared__ unsigned short tile[32][33];
    int tx = threadIdx.x & 31, ty = threadIdx.x >> 5;
    int n0 = blockIdx.x * 32, k0 = blockIdx.y * 32;
    for (int i = 0; i < 4; i++)
        tile[ty + 8 * i][tx] = f2bf(W[(k0 + ty + 8 * i) * 128 + n0 + tx]);
    __syncthreads();
    for (int i = 0; i < 4; i++)
        WT[(size_t)(n0 + ty + 8 * i) * 256 + k0 + tx] = tile[tx][ty + 8 * i];
}

// ---- fused: h = F@W+b (MFMA) -> w = exp(h.a2w+a2b) -> whT rows 0..128 ----
__global__ __launch_bounds__(256) void k_h_fused(const float* __restrict__ F,
                                                 const unsigned short* __restrict__ WT,
                                                 const float* __restrict__ bvec,
                                                 const float* __restrict__ a2w,
                                                 const float* __restrict__ a2b,
                                                 unsigned short* __restrict__ whT) {
    __shared__ __align__(16) unsigned short As[64 * 72];
    __shared__ __align__(16) unsigned short Bs[128 * 72];
    __shared__ __align__(16) unsigned short T[129 * 72];   // [col][row_local]
    __shared__ float bs[128], aw[128], ab_s;

    int t = threadIdx.x, lane = t & 63, wave = t >> 6;
    int rb = blockIdx.x * 64;
    if (t < 128) { bs[t] = bvec[t]; aw[t] = a2w[t]; }
    if (t == 0) ab_s = a2b[0];

    float4v acc[8];
    for (int c = 0; c < 8; c++) acc[c] = (float4v)0.0f;

    for (int kt = 0; kt < 4; kt++) {
        int k0 = kt * 64;
        for (int i = 0; i < 2; i++) {                       // A: 64x64 fp32 -> bf16
            int flat = t + 256 * i, row = flat >> 3, part = flat & 7;
            const float* fp = F + (size_t)(rb + row) * 256 + k0 + part * 8;
            float4 v0 = *reinterpret_cast<const float4*>(fp);
            float4 v1 = *reinterpret_cast<const float4*>(fp + 4);
            uint4 v;
            v.x = f2bf(v0.x) | ((uint32_t)f2bf(v0.y) << 16);
            v.y = f2bf(v0.z) | ((uint32_t)f2bf(v0.w) << 16);
            v.z = f2bf(v1.x) | ((uint32_t)f2bf(v1.y) << 16);
            v.w = f2bf(v1.z) | ((uint32_t)f2bf(v1.w) << 16);
            *reinterpret_cast<uint4*>(&As[row * 72 + part * 8]) = v;
        }
        for (int i = 0; i < 4; i++) {                       // B: 128x64 bf16 k-major
            int flat = t + 256 * i, n = flat >> 3, part = flat & 7;
            *reinterpret_cast<uint4*>(&Bs[n * 72 + part * 8]) =
                *reinterpret_cast<const uint4*>(WT + (size_t)n * 256 + k0 + part * 8);
        }
        __syncthreads();
        int m = lane & 15, kq = lane >> 4;
        for (int ks = 0; ks < 2; ks++) {
            short8 af = *reinterpret_cast<const short8*>(&As[(wave * 16 + m) * 72 + ks * 32 + kq * 8]);
            for (int c = 0; c < 8; c++) {
                short8 bfr = *reinterpret_cast<const short8*>(&Bs[(c * 16 + m) * 72 + ks * 32 + kq * 8]);
                acc[c] = __builtin_amdgcn_mfma_f32_16x16x32_bf16(af, bfr, acc[c], 0, 0, 0);
            }
        }
        __syncthreads();
    }

    // epilogue: bias, per-row a2 dot (reduce over 16-lane m-group), exp, scale
    int m = lane & 15, kq = lane >> 4;
    float hv[8][4], part[4];
    for (int r = 0; r < 4; r++) part[r] = 0.0f;
    for (int c = 0; c < 8; c++) {
        float bb = bs[c * 16 + m], a = aw[c * 16 + m];
        for (int r = 0; r < 4; r++) { hv[c][r] = acc[c][r] + bb; part[r] += hv[c][r] * a; }
    }
    for (int off = 1; off < 16; off <<= 1)
        for (int r = 0; r < 4; r++) part[r] += __shfl_xor(part[r], off, 64);
    float wr[4];
    for (int r = 0; r < 4; r++) {
        float e = fminf(fmaxf(part[r] + ab_s, -60.0f), 60.0f);
        wr[r] = expf(e);
    }
    int rl = wave * 16 + kq * 4;
    for (int c = 0; c < 8; c++)
        for (int r = 0; r < 4; r++)
            T[(c * 16 + m) * 72 + rl + r] = f2bf(hv[c][r] * wr[r]);
    if (m == 0)
        for (int r = 0; r < 4; r++)
            T[128 * 72 + rl + r] = f2bf(wr[r]);
    __syncthreads();

    for (int i = 0; i < 5; i++) {                           // 129 rows x 64 shorts
        int flat = t + 256 * i;
        if (flat < 1032) {
            int row = flat >> 3, part = flat & 7;
            *reinterpret_cast<uint4*>(whT + (size_t)row * 8192 + rb + part * 8) =
                *reinterpret_cast<const uint4*>(&T[row * 72 + part * 8]);
        }
    }
}

// ---- KMAIN: out[32 rows] = (adj @ wh) / (adj @ w) for one block. ----
// 8 waves: wave w covers K in [w*1024, (w+1)*1024). No barriers in K-loop;
// depth-1 register prefetch of A(adj int32->bf16) and B(whT, L2-resident).
// End: LDS reduction over waves (8 sequential slots), fused divide, plain store.
__global__ __launch_bounds__(512, 2) void k_agg(const int* __restrict__ adj,
                                                const unsigned short* __restrict__ whT,
                                                float* __restrict__ out) {
    __shared__ float red[32][148];
    int t = threadIdx.x, lane = t & 63, wave = t >> 6;   // 8 waves
    int m = lane & 15, kq = lane >> 4;
    int rb = blockIdx.x * 32;
    int kbase = wave * 1024;

    float4v acc[2][9];
    #pragma unroll
    for (int s = 0; s < 2; s++)
        for (int c = 0; c < 9; c++) acc[s][c] = (float4v)0.0f;

    const int* a0 = adj + (size_t)(rb + m) * 8192 + kbase + kq * 8;
    const int* a1 = a0 + (size_t)16 * 8192;
    const unsigned short* bp = whT + (size_t)m * 8192 + kbase + kq * 8;

    // prologue: iter-0 fragments
    int4 x0 = *reinterpret_cast<const int4*>(a0);
    int4 x1 = *reinterpret_cast<const int4*>(a0 + 4);
    int4 y0 = *reinterpret_cast<const int4*>(a1);
    int4 y1 = *reinterpret_cast<const int4*>(a1 + 4);
    short8 bv[9];
    #pragma unroll
    for (int c = 0; c < 9; c++)
        bv[c] = *reinterpret_cast<const short8*>(bp + (size_t)c * 131072);

    #pragma unroll 2
    for (int it = 0; it < 32; ++it) {
        int nk = (it < 31 ? it + 1 : 31) * 32;             // clamp: last iter re-loads (safe)
        int4 nx0 = *reinterpret_cast<const int4*>(a0 + nk);
        int4 nx1 = *reinterpret_cast<const int4*>(a0 + nk + 4);
        int4 ny0 = *reinterpret_cast<const int4*>(a1 + nk);
        int4 ny1 = *reinterpret_cast<const int4*>(a1 + nk + 4);
        short8 nb[9];
        #pragma unroll
        for (int c = 0; c < 9; c++)
            nb[c] = *reinterpret_cast<const short8*>(bp + nk + (size_t)c * 131072);

        short8 af0 = pack01(x0, x1), af1 = pack01(y0, y1);
        #pragma unroll
        for (int c = 0; c < 9; c++) {
            acc[0][c] = __builtin_amdgcn_mfma_f32_16x16x32_bf16(af0, bv[c], acc[0][c], 0, 0, 0);
            acc[1][c] = __builtin_amdgcn_mfma_f32_16x16x32_bf16(af1, bv[c], acc[1][c], 0, 0, 0);
        }
        x0 = nx0; x1 = nx1; y0 = ny0; y1 = ny1;
        #pragma unroll
        for (int c = 0; c < 9; c++) bv[c] = nb[c];
    }

    // LDS reduction across the 8 waves
    for (int i = t; i < 32 * 148; i += 512)
        (&red[0][0])[i] = 0.0f;
    __syncthreads();
    for (int w = 0; w < 8; w++) {
        if (wave == w) {
            #pragma unroll
            for (int s = 0; s < 2; s++)
                for (int c = 0; c < 9; c++)
                    for (int rr = 0; rr < 4; rr++)
                        red[s * 16 + kq * 4 + rr][c * 16 + m] += acc[s][c][rr];
        }
        __syncthreads();
    }

    // fused epilogue: out = num / den, plain coalesced stores
    for (int i = t; i < 32 * 128; i += 512) {
        int r = i >> 7, c = i & 127;
        out[(size_t)(rb + r) * 128 + c] = red[r][c] / red[r][128];
    }
}

extern "C" void kernel_launch(void* const* d_in, const int* in_sizes, int n_in,
                              void* d_out, int out_size, void* d_ws, size_t ws_size,
                              hipStream_t stream) {
    const float* F   = (const float*)d_in[0];     // [8192][256]
    const int*   adj = (const int*)d_in[1];       // [8192][8192] 0/1
    const float* W   = (const float*)d_in[2];     // [256][128]
    const float* bv  = (const float*)d_in[3];     // [128]
    const float* a2w = (const float*)d_in[6];     // [128]  (a1 cancels; d_in[4],[5] unused)
    const float* a2b = (const float*)d_in[7];     // [1]
    float* out = (float*)d_out;                   // [8192][128]

    char* ws = (char*)d_ws;
    unsigned short* whT = (unsigned short*)(ws);            // 2,359,296 B (144 x 8192 bf16;
                                                            //  rows 129-143 unused poison, never read)
    unsigned short* WT  = (unsigned short*)(ws + 2359296);  //    65,536 B  (total 2.42 MB)

    k_transpose_w<<<dim3(4, 8), 256, 0, stream>>>(W, WT);
    k_h_fused<<<128, 256, 0, stream>>>(F, WT, bv, a2w, a2b, whT);
    k_agg<<<256, 512, 0, stream>>>(adj, whT, out);
}